// Round 13
// baseline (187.764 us; speedup 1.0000x reference)
//
#include <hip/hip_runtime.h>

#define DM   1024
#define LSEQ 1024
#define BATCH 8
#define MROWS (BATCH*LSEQ)   // 8192

typedef __attribute__((ext_vector_type(8))) short  bf16x8;
typedef __attribute__((ext_vector_type(4))) float  f32x4;
typedef __attribute__((ext_vector_type(4))) unsigned short u16x4;
typedef __attribute__((ext_vector_type(8))) unsigned short u16x8;

__device__ inline unsigned short f2bf(float f){
  unsigned u = __builtin_bit_cast(unsigned, f);
  u += 0x7fffu + ((u >> 16) & 1u);          // RNE
  return (unsigned short)(u >> 16);
}
__device__ inline float bf2f(unsigned short h){
  unsigned u = (unsigned)h << 16;
  return __builtin_bit_cast(float, u);
}

__device__ inline void gload_lds16(const void* g, void* l){
  __builtin_amdgcn_global_load_lds(
      (const __attribute__((address_space(1))) void*)g,
      (__attribute__((address_space(3))) void*)l,
      16, 0, 0);
}

// ================= 128x32-tile helpers (scores / pv / Mt — proven path) =====
__device__ inline void stage_gload(const unsigned short* src, int row0, int k0,
                                   unsigned short* lds, int wave, int lane)
{
  int fr = lane & 15, kg = lane >> 4;
  #pragma unroll
  for (int it = 0; it < 2; ++it){
    int nb = it*4 + wave;                 // wave-uniform
    gload_lds16(src + (size_t)(row0 + nb*16 + fr)*1024 + k0 + kg*8,
                lds + nb*512);
  }
}

__device__ inline void mma_step(const unsigned short* As, const unsigned short* Bs,
                                int wrb4, int wcb4, int fr, int kg,
                                f32x4 acc[4][4])
{
  bf16x8 av[4], bv[4];
  #pragma unroll
  for (int mi = 0; mi < 4; ++mi)
    av[mi] = *(const bf16x8*)(As + (size_t)(((wrb4 + mi)*4 + kg)*16 + fr)*8);
  #pragma unroll
  for (int ni = 0; ni < 4; ++ni)
    bv[ni] = *(const bf16x8*)(Bs + (size_t)(((wcb4 + ni)*4 + kg)*16 + fr)*8);
  #pragma unroll
  for (int mi = 0; mi < 4; ++mi)
    #pragma unroll
    for (int ni = 0; ni < 4; ++ni)
      acc[mi][ni] = __builtin_amdgcn_mfma_f32_16x16x32_bf16(av[mi], bv[ni], acc[mi][ni], 0, 0, 0);
}

// depth-3 ring (R4, proven): ONE raw barrier per K-step, counted vmcnt.
__device__ inline void gemm_ring(const unsigned short* __restrict__ A, int m0,
                                 const unsigned short* __restrict__ B, int n0,
                                 unsigned short* smem, int nk,
                                 int wave, int lane,
                                 int wrb4, int wcb4, int fr, int kg,
                                 f32x4 acc[4][4])
{
  stage_gload(A, m0, 0,  smem,        wave, lane);
  stage_gload(B, n0, 0,  smem + 4096, wave, lane);
  stage_gload(A, m0, 32, smem + 8192, wave, lane);
  stage_gload(B, n0, 32, smem + 8192 + 4096, wave, lane);
  for (int kt = 0; kt < nk; ++kt){
    if (kt + 1 < nk) asm volatile("s_waitcnt vmcnt(4)\n\ts_barrier" ::: "memory");
    else             asm volatile("s_waitcnt vmcnt(0)\n\ts_barrier" ::: "memory");
    unsigned short* buf = smem + (unsigned)(kt % 3) * 8192;
    mma_step(buf, buf + 4096, wrb4, wcb4, fr, kg, acc);
    if (kt + 2 < nk){
      unsigned short* nb = smem + (unsigned)((kt + 2) % 3) * 8192;
      stage_gload(A, m0, (kt+2)*32, nb,        wave, lane);
      stage_gload(B, n0, (kt+2)*32, nb + 4096, wave, lane);
    }
  }
}

// ---------------- X fp32 -> bf16 bulk convert (8M elems per z) --------------
__global__ __launch_bounds__(256) void k_cvt(
    const float* __restrict__ X0, const float* __restrict__ X1, const float* __restrict__ X2,
    unsigned short* __restrict__ Y0, unsigned short* __restrict__ Y1, unsigned short* __restrict__ Y2)
{
  int z = blockIdx.z;
  const float* X = z==0 ? X0 : (z==1 ? X1 : X2);
  unsigned short* Y = z==0 ? Y0 : (z==1 ? Y1 : Y2);
  size_t i = ((size_t)blockIdx.x*256 + threadIdx.x)*8;
  f32x4 a = *(const f32x4*)(X+i);
  f32x4 b = *(const f32x4*)(X+i+4);
  u16x8 o;
  o[0]=f2bf(a[0]); o[1]=f2bf(a[1]); o[2]=f2bf(a[2]); o[3]=f2bf(a[3]);
  o[4]=f2bf(b[0]); o[5]=f2bf(b[1]); o[6]=f2bf(b[2]); o[7]=f2bf(b[3]);
  *(u16x8*)(Y+i) = o;
}

// ---------------- W fp32 -> bf16 (row-major copy, 1M elems per z) -----------
__global__ __launch_bounds__(256) void k_cvtw(
    const float* __restrict__ W0, const float* __restrict__ W1,
    unsigned short* __restrict__ Y0, unsigned short* __restrict__ Y1)
{
  int z = blockIdx.z;
  const float* X = z==0 ? W0 : W1;
  unsigned short* Y = z==0 ? Y0 : Y1;
  size_t i = ((size_t)blockIdx.x*256 + threadIdx.x)*8;
  f32x4 a = *(const f32x4*)(X+i);
  f32x4 b = *(const f32x4*)(X+i+4);
  u16x8 o;
  o[0]=f2bf(a[0]); o[1]=f2bf(a[1]); o[2]=f2bf(a[2]); o[3]=f2bf(a[3]);
  o[4]=f2bf(b[0]); o[5]=f2bf(b[1]); o[6]=f2bf(b[2]); o[7]=f2bf(b[3]);
  *(u16x8*)(Y+i) = o;
}

// ---------------- Wv transpose + convert:  WvT[n][k] = bf16(Wv[k][n]) -------
__global__ __launch_bounds__(256) void k_transpose_wv(
    const float* __restrict__ W, unsigned short* __restrict__ T)
{
  __shared__ unsigned short tile[64*68];
  int n0 = blockIdx.x*64, k0 = blockIdx.y*64;
  int tid = threadIdx.x;
  {
    int r = tid >> 4;                 // 0..15
    int c = (tid & 15) * 4;
    #pragma unroll
    for (int it = 0; it < 4; ++it){
      f32x4 v = *(const f32x4*)(W + (size_t)(k0 + it*16 + r)*DM + n0 + c);
      u16x4 h; h[0]=f2bf(v[0]); h[1]=f2bf(v[1]); h[2]=f2bf(v[2]); h[3]=f2bf(v[3]);
      *(u16x4*)(tile + (it*16 + r)*68 + c) = h;
    }
  }
  __syncthreads();
  {
    int nl = tid >> 2;                // 0..63
    int kc = (tid & 3) * 16;
    u16x8 o;
    #pragma unroll
    for (int j = 0; j < 8; ++j) o[j] = tile[(kc+j)*68 + nl];
    *(u16x8*)(T + (size_t)(n0+nl)*DM + k0 + kc) = o;
    #pragma unroll
    for (int j = 0; j < 8; ++j) o[j] = tile[(kc+8+j)*68 + nl];
    *(u16x8*)(T + (size_t)(n0+nl)*DM + k0 + kc + 8) = o;
  }
}

// ---------------- Mt[c][d] = bf16( sum_e Wk[c][e] * Wq[d][e] ) --------------
__global__ __launch_bounds__(256) void k_mt(
    const unsigned short* __restrict__ Wkbf, const unsigned short* __restrict__ Wqbf,
    unsigned short* __restrict__ Mt)
{
  __shared__ __align__(16) unsigned short smem[24576];
  int m0 = blockIdx.y*128, n0 = blockIdx.x*128;
  int tid = threadIdx.x, wave = tid >> 6, lane = tid & 63;
  int wrb4 = (wave >> 1)*4, wcb4 = (wave & 1)*4, fr = lane & 15, kg = lane >> 4;
  f32x4 acc[4][4] = {};
  gemm_ring(Wkbf, m0, Wqbf, n0, smem, 32, wave, lane, wrb4, wcb4, fr, kg, acc);
  #pragma unroll
  for (int mi = 0; mi < 4; ++mi)
    #pragma unroll
    for (int ni = 0; ni < 4; ++ni){
      int r = m0 + wrb4*16 + mi*16 + kg*4;
      int c = n0 + wcb4*16 + ni*16 + fr;
      #pragma unroll
      for (int i = 0; i < 4; ++i)
        Mt[(size_t)(r+i)*DM + c] = f2bf(acc[mi][ni][i]);
    }
}

// ================= projection GEMM (R6-proven): BM=256 BN=128 BK=64 =========
// z=0: qm = Xq @ Mt (plain bf16 out); z=1: vT = (Xv @ Wv)^T (transposed out)

#define WB6 asm volatile("s_waitcnt vmcnt(6)\n\ts_barrier" ::: "memory")
#define WB0 asm volatile("s_waitcnt vmcnt(0)\n\ts_barrier" ::: "memory")
#define LB  asm volatile("s_waitcnt lgkmcnt(0)\n\ts_barrier" ::: "memory")

#define STAGEALL(AB, BB, KOF) do{ \
  _Pragma("unroll") for (int i_=0;i_<4;++i_) gload_lds16(pa[i_] + (KOF), smem + (AB) + (wave+8*i_)*512); \
  _Pragma("unroll") for (int i_=0;i_<2;++i_) gload_lds16(pb[i_] + (KOF), smem + (BB) + (wave+8*i_)*512); }while(0)

#define PHASEBODY(AB, BB, KOF, DOSTAGE, WAITM) do{ \
  WAITM; \
  bf16x8 av[2][4], bv[2][4]; \
  _Pragma("unroll") for (int s_=0;s_<2;++s_){ \
    _Pragma("unroll") for (int i_=0;i_<4;++i_) \
      av[s_][i_] = *(const bf16x8*)(smem + (AB) + s_*8192 + (wr4+i_)*512 + lane8); \
    _Pragma("unroll") for (int i_=0;i_<4;++i_) \
      bv[s_][i_] = *(const bf16x8*)(smem + (BB) + s_*4096 + (wc4+i_)*512 + lane8); \
  } \
  LB; \
  if (DOSTAGE){ \
    _Pragma("unroll") for (int i_=0;i_<4;++i_) gload_lds16(pa[i_] + (KOF), smem + (AB) + (wave+8*i_)*512); \
    _Pragma("unroll") for (int i_=0;i_<2;++i_) gload_lds16(pb[i_] + (KOF), smem + (BB) + (wave+8*i_)*512); \
  } \
  _Pragma("unroll") for (int s_=0;s_<2;++s_) \
    _Pragma("unroll") for (int mi_=0;mi_<4;++mi_) \
      _Pragma("unroll") for (int ni_=0;ni_<4;++ni_) \
        acc[mi_][ni_] = __builtin_amdgcn_mfma_f32_16x16x32_bf16(av[s_][mi_], bv[s_][ni_], acc[mi_][ni_], 0,0,0); \
}while(0)

__global__ __launch_bounds__(512, 2) void k_proj(
    const unsigned short* __restrict__ Xq, const unsigned short* __restrict__ Xv,
    const unsigned short* __restrict__ Mt, const unsigned short* __restrict__ WvT,
    unsigned short* __restrict__ qm, unsigned short* __restrict__ vT)
{
  __shared__ __align__(16) unsigned short smem[49152];     // 96 KB
  int z = blockIdx.z;
  const unsigned short* X  = z==0 ? Xq : Xv;
  const unsigned short* Wt = z==0 ? Mt : WvT;
  // 256 blocks/z = 32 M-tiles x 8 N-tiles; XCD-chunked swizzle (256%8==0)
  int bid = blockIdx.x;
  int t8  = (bid & 7)*32 + (bid >> 3);
  int mt  = t8 >> 3, nt = t8 & 7;
  int m0 = mt*256, n0 = nt*128;
  int tid = threadIdx.x, wave = tid >> 6, lane = tid & 63;
  int wr = wave >> 1, wc = wave & 1;
  int fr = lane & 15, kg = lane >> 4;
  int wr4 = wr*4, wc4 = wc*4, lane8 = lane*8;

  const unsigned short* pa[4];
  const unsigned short* pb[2];
  #pragma unroll
  for (int i = 0; i < 4; ++i){
    int idx = wave + 8*i, s = idx >> 4, nb = idx & 15;
    pa[i] = X + (size_t)(m0 + nb*16 + fr)*1024 + s*32 + kg*8;
  }
  #pragma unroll
  for (int i = 0; i < 2; ++i){
    int idx = wave + 8*i, s = idx >> 3, nb = idx & 7;
    pb[i] = Wt + (size_t)(n0 + nb*16 + fr)*1024 + s*32 + kg*8;
  }

  f32x4 acc[4][4] = {};

  STAGEALL(0,     16384, 0);        // tile 0 -> buf0
  STAGEALL(24576, 40960, 64);       // tile 1 -> buf1
  #pragma unroll
  for (int g = 0; g < 7; ++g){
    PHASEBODY(0,     16384, (2*g+2)*64, true, WB6);   // tiles 0,2,..12
    PHASEBODY(24576, 40960, (2*g+3)*64, true, WB6);   // tiles 1,3,..13
  }
  PHASEBODY(0,     16384, 0, false, WB6);             // tile 14
  PHASEBODY(24576, 40960, 0, false, WB0);             // tile 15

  if (z == 0){
    #pragma unroll
    for (int mi = 0; mi < 4; ++mi)
      #pragma unroll
      for (int ni = 0; ni < 4; ++ni){
        int r = m0 + wr*64 + mi*16 + kg*4;
        int c = n0 + wc*64 + ni*16 + fr;
        #pragma unroll
        for (int i = 0; i < 4; ++i)
          qm[(size_t)(r+i)*DM + c] = f2bf(acc[mi][ni][i]);
      }
  } else {
    __syncthreads();                                  // pipeline drained; reuse smem
    unsigned short* Tt = smem;                        // [128 d][264] transposed tile
    #pragma unroll
    for (int mi = 0; mi < 4; ++mi)
      #pragma unroll
      for (int ni = 0; ni < 4; ++ni){
        int d2 = wc*64 + ni*16 + fr;                  // 0..127
        int l  = wr*64 + mi*16 + kg*4;                // 0..255
        u16x4 t;
        t[0]=f2bf(acc[mi][ni][0]); t[1]=f2bf(acc[mi][ni][1]);
        t[2]=f2bf(acc[mi][ni][2]); t[3]=f2bf(acc[mi][ni][3]);
        *(u16x4*)(Tt + d2*264 + l) = t;
      }
    __syncthreads();
    int b = m0 >> 10, l0 = m0 & 1023;
    int row = tid >> 2, ch = tid & 3;                 // 128 rows x 4 chunks of 64 shorts
    unsigned short* dst = vT + ((size_t)b << 20) + (size_t)(n0 + row)*LSEQ + l0 + ch*64;
    const unsigned short* srcT = Tt + row*264 + ch*64;
    #pragma unroll
    for (int k = 0; k < 8; ++k)
      *(u16x8*)(dst + k*8) = *(const u16x8*)(srcT + k*8);
  }
}

// ---------------- scores: S = bf16((qm . Xk)/32), causal block-skip ---------
__global__ __launch_bounds__(256) void k_scores(
    const unsigned short* __restrict__ q, const unsigned short* __restrict__ k,
    unsigned short* __restrict__ S)
{
  __shared__ __align__(16) unsigned short smem[24576];
  int b = blockIdx.z;
  int raw = blockIdx.x + 8*blockIdx.y;
  int tile = (raw & 7)*8 + (raw >> 3);
  int kt = tile & 7, qt = tile >> 3;
  if (kt > qt) return;                               // block-uniform exit
  const unsigned short* qb = q + ((size_t)b << 20);
  const unsigned short* kb = k + ((size_t)b << 20);
  int m0 = qt*128, n0 = kt*128;
  int tid = threadIdx.x, wave = tid >> 6, lane = tid & 63;
  int wrb4 = (wave >> 1)*4, wcb4 = (wave & 1)*4, fr = lane & 15, kg = lane >> 4;
  f32x4 acc[4][4] = {};
  gemm_ring(qb, m0, kb, n0, smem, 32, wave, lane, wrb4, wcb4, fr, kg, acc);

  unsigned short* Sb = S + ((size_t)b << 20);
  const float scale = 0.03125f;                      // 1/sqrt(1024)
  #pragma unroll
  for (int mi = 0; mi < 4; ++mi)
    #pragma unroll
    for (int ni = 0; ni < 4; ++ni){
      int r = m0 + wrb4*16 + mi*16 + kg*4;
      int c = n0 + wcb4*16 + ni*16 + fr;
      #pragma unroll
      for (int i = 0; i < 4; ++i)
        Sb[(size_t)(r+i)*LSEQ + c] = f2bf(acc[mi][ni][i] * scale);
    }
}

// ---------------- causal row softmax (bf16 S in): P bf16 --------------------
__global__ __launch_bounds__(256) void k_softmax(
    const unsigned short* __restrict__ S, unsigned short* __restrict__ P)
{
  int gq = blockIdx.x;                                // 0..8191
  int qq = gq & 1023;
  const unsigned short* row = S + (size_t)gq * 1024;
  unsigned short* prow = P + (size_t)gq * 1024;
  int tid = threadIdx.x;

  u16x4 hv = *(const u16x4*)(row + tid*4);
  float vals[4];
  float m = -1e30f;
  #pragma unroll
  for (int e = 0; e < 4; ++e){
    int idx = tid*4 + e;
    vals[e] = (idx <= qq) ? bf2f(hv[e]) : -1e30f;
    m = fmaxf(m, vals[e]);
  }
  #pragma unroll
  for (int off = 32; off >= 1; off >>= 1) m = fmaxf(m, __shfl_xor(m, off));
  __shared__ float redm[4], reds[4];
  if ((tid & 63) == 0) redm[tid >> 6] = m;
  __syncthreads();
  m = fmaxf(fmaxf(redm[0], redm[1]), fmaxf(redm[2], redm[3]));

  float e4[4], s = 0.f;
  #pragma unroll
  for (int e = 0; e < 4; ++e){
    int idx = tid*4 + e;
    e4[e] = (idx <= qq) ? __expf(vals[e] - m) : 0.f;
    s += e4[e];
  }
  #pragma unroll
  for (int off = 32; off >= 1; off >>= 1) s += __shfl_xor(s, off);
  if ((tid & 63) == 0) reds[tid >> 6] = s;
  __syncthreads();
  s = reds[0] + reds[1] + reds[2] + reds[3];
  float inv = 1.f / s;

  u16x4 o;
  #pragma unroll
  for (int e = 0; e < 4; ++e) o[e] = f2bf(e4[e] * inv);
  *(u16x4*)(prow + tid*4) = o;
}

// ---------------- PV: O = P @ vT^T, diag-cut K, longest-first ---------------
__global__ __launch_bounds__(256) void k_pv(
    const unsigned short* __restrict__ P, const unsigned short* __restrict__ vT,
    float* __restrict__ O)
{
  __shared__ __align__(16) unsigned short smem[24576];
  int b = blockIdx.z;
  int raw = blockIdx.x + 8*blockIdx.y;
  int qt = 7 - (raw & 7);                             // longest-K blocks dispatch first
  int dt = raw >> 3;
  const unsigned short* Pb = P  + ((size_t)b << 20);
  const unsigned short* Vb = vT + ((size_t)b << 20);
  int m0 = qt*128, n0 = dt*128;
  int tid = threadIdx.x, wave = tid >> 6, lane = tid & 63;
  int wrb4 = (wave >> 1)*4, wcb4 = (wave & 1)*4, fr = lane & 15, kg = lane >> 4;
  f32x4 acc[4][4] = {};
  int nk = (qt + 1) * 4;                              // kk in [0,(qt+1)*128); >= 4
  gemm_ring(Pb, m0, Vb, n0, smem, nk, wave, lane, wrb4, wcb4, fr, kg, acc);

  float* Ob = O + ((size_t)(b*1024 + m0) << 10);
  #pragma unroll
  for (int mi = 0; mi < 4; ++mi)
    #pragma unroll
    for (int ni = 0; ni < 4; ++ni){
      int r = wrb4*16 + mi*16 + kg*4;
      int c = n0 + wcb4*16 + ni*16 + fr;
      #pragma unroll
      for (int i = 0; i < 4; ++i)
        Ob[(size_t)(r+i)*DM + c] = acc[mi][ni][i];
    }
}

extern "C" void kernel_launch(void* const* d_in, const int* in_sizes, int n_in,
                              void* d_out, int out_size, void* d_ws, size_t ws_size,
                              hipStream_t stream)
{
  const float* query = (const float*)d_in[0];
  const float* key   = (const float*)d_in[1];
  const float* value = (const float*)d_in[2];
  const float* Wq    = (const float*)d_in[3];
  const float* Wk    = (const float*)d_in[4];
  const float* Wv    = (const float*)d_in[5];
  float* out = (float*)d_out;

  // ws layout (shorts), 70 MB total — proven footprint:
  unsigned short* ws = (unsigned short*)d_ws;
  unsigned short* qm   = ws;                                  // 8M  (Xq @ WqWk^T)
  unsigned short* vT   = qm   + (size_t)MROWS*DM;             // 8M  [B][D][L]
  unsigned short* Xk   = vT   + (size_t)MROWS*DM;             // 8M  bf16 key input
  unsigned short* PXv  = Xk   + (size_t)MROWS*DM;             // 8M  Xv, later P
  unsigned short* Wqbf = PXv  + (size_t)MROWS*DM;             // 1M
  unsigned short* Wkbf = Wqbf + (size_t)DM*DM;                // 1M
  unsigned short* WvT  = Wkbf + (size_t)DM*DM;                // 1M

  // d_out dead-buffer reuse (32 MB):
  //   Xq (16 MB) + Mt (2 MB) live until k_proj is done.
  //   S bf16 (16 MB) then overlaps the dead Xq region; k_pv finally
  //   overwrites all of d_out with O fp32.
  unsigned short* outU = (unsigned short*)d_out;
  unsigned short* Xq = outU;                                  // 8M shorts
  unsigned short* Mt = outU + (size_t)MROWS*DM;               // 1M shorts
  unsigned short* S  = outU;                                  // bf16 scores (Xq dead)

  dim3 blk(256);
  k_transpose_wv<<<dim3(16,16,1), blk, 0, stream>>>(Wv, WvT);
  k_cvtw        <<<dim3(512,1,2), blk, 0, stream>>>(Wq, Wk, Wqbf, Wkbf);
  k_cvt         <<<dim3(4096,1,3), blk, 0, stream>>>(query, key, value, Xq, Xk, PXv);
  k_mt          <<<dim3(8,8,1),   blk, 0, stream>>>(Wkbf, Wqbf, Mt);
  k_proj        <<<dim3(256,1,2), dim3(512), 0, stream>>>(Xq, PXv, Mt, WvT, qm, vT);
  k_scores      <<<dim3(8,8,8),   blk, 0, stream>>>(qm, Xk, S);
  k_softmax     <<<dim3(8192),    blk, 0, stream>>>(S, PXv);
  k_pv          <<<dim3(8,8,8),   blk, 0, stream>>>(PXv, vT, out);
}

// Round 14
// 179.780 us; speedup vs baseline: 1.0444x; 1.0444x over previous
//
#include <hip/hip_runtime.h>

#define DM   1024
#define LSEQ 1024
#define BATCH 8
#define MROWS (BATCH*LSEQ)   // 8192

typedef __attribute__((ext_vector_type(8))) short  bf16x8;
typedef __attribute__((ext_vector_type(4))) float  f32x4;
typedef __attribute__((ext_vector_type(4))) unsigned short u16x4;
typedef __attribute__((ext_vector_type(8))) unsigned short u16x8;

__device__ inline unsigned short f2bf(float f){
  unsigned u = __builtin_bit_cast(unsigned, f);
  u += 0x7fffu + ((u >> 16) & 1u);          // RNE
  return (unsigned short)(u >> 16);
}
__device__ inline float bf2f(unsigned short h){
  unsigned u = (unsigned)h << 16;
  return __builtin_bit_cast(float, u);
}

__device__ inline void gload_lds16(const void* g, void* l){
  __builtin_amdgcn_global_load_lds(
      (const __attribute__((address_space(1))) void*)g,
      (__attribute__((address_space(3))) void*)l,
      16, 0, 0);
}

// ================= 128x32-tile helpers (scores / pv / mt — proven path) =====
__device__ inline void stage_gload(const unsigned short* src, int row0, int k0,
                                   unsigned short* lds, int wave, int lane)
{
  int fr = lane & 15, kg = lane >> 4;
  #pragma unroll
  for (int it = 0; it < 2; ++it){
    int nb = it*4 + wave;                 // wave-uniform
    gload_lds16(src + (size_t)(row0 + nb*16 + fr)*1024 + k0 + kg*8,
                lds + nb*512);
  }
}

__device__ inline void mma_step(const unsigned short* As, const unsigned short* Bs,
                                int wrb4, int wcb4, int fr, int kg,
                                f32x4 acc[4][4])
{
  bf16x8 av[4], bv[4];
  #pragma unroll
  for (int mi = 0; mi < 4; ++mi)
    av[mi] = *(const bf16x8*)(As + (size_t)(((wrb4 + mi)*4 + kg)*16 + fr)*8);
  #pragma unroll
  for (int ni = 0; ni < 4; ++ni)
    bv[ni] = *(const bf16x8*)(Bs + (size_t)(((wcb4 + ni)*4 + kg)*16 + fr)*8);
  #pragma unroll
  for (int mi = 0; mi < 4; ++mi)
    #pragma unroll
    for (int ni = 0; ni < 4; ++ni)
      acc[mi][ni] = __builtin_amdgcn_mfma_f32_16x16x32_bf16(av[mi], bv[ni], acc[mi][ni], 0, 0, 0);
}

// depth-3 ring (R4, proven): ONE raw barrier per K-step, counted vmcnt.
__device__ inline void gemm_ring(const unsigned short* __restrict__ A, int m0,
                                 const unsigned short* __restrict__ B, int n0,
                                 unsigned short* smem, int nk,
                                 int wave, int lane,
                                 int wrb4, int wcb4, int fr, int kg,
                                 f32x4 acc[4][4])
{
  stage_gload(A, m0, 0,  smem,        wave, lane);
  stage_gload(B, n0, 0,  smem + 4096, wave, lane);
  stage_gload(A, m0, 32, smem + 8192, wave, lane);
  stage_gload(B, n0, 32, smem + 8192 + 4096, wave, lane);
  for (int kt = 0; kt < nk; ++kt){
    if (kt + 1 < nk) asm volatile("s_waitcnt vmcnt(4)\n\ts_barrier" ::: "memory");
    else             asm volatile("s_waitcnt vmcnt(0)\n\ts_barrier" ::: "memory");
    unsigned short* buf = smem + (unsigned)(kt % 3) * 8192;
    mma_step(buf, buf + 4096, wrb4, wcb4, fr, kg, acc);
    if (kt + 2 < nk){
      unsigned short* nb = smem + (unsigned)((kt + 2) % 3) * 8192;
      stage_gload(A, m0, (kt+2)*32, nb,        wave, lane);
      stage_gload(B, n0, (kt+2)*32, nb + 4096, wave, lane);
    }
  }
}

// ---------------- prep: all fp32->bf16 conversions in ONE launch ------------
// bid [0,12288): X cvt (z=bid/4096); [12288,13312): W cvt (z=(bid-12288)/512);
// [13312,13568): Wv transpose.
__global__ __launch_bounds__(256) void k_prep(
    const float* __restrict__ query, const float* __restrict__ key, const float* __restrict__ value,
    const float* __restrict__ Wq, const float* __restrict__ Wk, const float* __restrict__ Wv,
    unsigned short* __restrict__ Xq, unsigned short* __restrict__ Xk, unsigned short* __restrict__ Xv,
    unsigned short* __restrict__ Wqbf, unsigned short* __restrict__ Wkbf,
    unsigned short* __restrict__ WvT)
{
  int bid = blockIdx.x;
  int tid = threadIdx.x;
  if (bid < 12288){
    int z = bid >> 12, ib = bid & 4095;
    const float* X = z==0 ? query : (z==1 ? key : value);
    unsigned short* Y = z==0 ? Xq : (z==1 ? Xk : Xv);
    size_t i = ((size_t)ib*256 + tid)*8;
    f32x4 a = *(const f32x4*)(X+i);
    f32x4 b = *(const f32x4*)(X+i+4);
    u16x8 o;
    o[0]=f2bf(a[0]); o[1]=f2bf(a[1]); o[2]=f2bf(a[2]); o[3]=f2bf(a[3]);
    o[4]=f2bf(b[0]); o[5]=f2bf(b[1]); o[6]=f2bf(b[2]); o[7]=f2bf(b[3]);
    *(u16x8*)(Y+i) = o;
  } else if (bid < 13312){
    int b2 = bid - 12288;
    int z = b2 >> 9, ib = b2 & 511;
    const float* X = z==0 ? Wq : Wk;
    unsigned short* Y = z==0 ? Wqbf : Wkbf;
    size_t i = ((size_t)ib*256 + tid)*8;
    f32x4 a = *(const f32x4*)(X+i);
    f32x4 b = *(const f32x4*)(X+i+4);
    u16x8 o;
    o[0]=f2bf(a[0]); o[1]=f2bf(a[1]); o[2]=f2bf(a[2]); o[3]=f2bf(a[3]);
    o[4]=f2bf(b[0]); o[5]=f2bf(b[1]); o[6]=f2bf(b[2]); o[7]=f2bf(b[3]);
    *(u16x8*)(Y+i) = o;
  } else {
    __shared__ unsigned short tile[64*68];
    int b2 = bid - 13312;
    int n0 = (b2 & 15)*64, k0 = (b2 >> 4)*64;
    {
      int r = tid >> 4;                 // 0..15
      int c = (tid & 15) * 4;
      #pragma unroll
      for (int it = 0; it < 4; ++it){
        f32x4 v = *(const f32x4*)(Wv + (size_t)(k0 + it*16 + r)*DM + n0 + c);
        u16x4 h; h[0]=f2bf(v[0]); h[1]=f2bf(v[1]); h[2]=f2bf(v[2]); h[3]=f2bf(v[3]);
        *(u16x4*)(tile + (it*16 + r)*68 + c) = h;
      }
    }
    __syncthreads();
    {
      int nl = tid >> 2;                // 0..63
      int kc = (tid & 3) * 16;
      u16x8 o;
      #pragma unroll
      for (int j = 0; j < 8; ++j) o[j] = tile[(kc+j)*68 + nl];
      *(u16x8*)(WvT + (size_t)(n0+nl)*DM + k0 + kc) = o;
      #pragma unroll
      for (int j = 0; j < 8; ++j) o[j] = tile[(kc+8+j)*68 + nl];
      *(u16x8*)(WvT + (size_t)(n0+nl)*DM + k0 + kc + 8) = o;
    }
  }
}

// ---------------- Mt[c][d] = bf16( sum_e Wk[c][e] * Wq[d][e] ) --------------
__global__ __launch_bounds__(256) void k_mt(
    const unsigned short* __restrict__ Wkbf, const unsigned short* __restrict__ Wqbf,
    unsigned short* __restrict__ Mt)
{
  __shared__ __align__(16) unsigned short smem[24576];
  int m0 = blockIdx.y*128, n0 = blockIdx.x*128;
  int tid = threadIdx.x, wave = tid >> 6, lane = tid & 63;
  int wrb4 = (wave >> 1)*4, wcb4 = (wave & 1)*4, fr = lane & 15, kg = lane >> 4;
  f32x4 acc[4][4] = {};
  gemm_ring(Wkbf, m0, Wqbf, n0, smem, 32, wave, lane, wrb4, wcb4, fr, kg, acc);
  #pragma unroll
  for (int mi = 0; mi < 4; ++mi)
    #pragma unroll
    for (int ni = 0; ni < 4; ++ni){
      int r = m0 + wrb4*16 + mi*16 + kg*4;
      int c = n0 + wcb4*16 + ni*16 + fr;
      #pragma unroll
      for (int i = 0; i < 4; ++i)
        Mt[(size_t)(r+i)*DM + c] = f2bf(acc[mi][ni][i]);
    }
}

// ================= projection GEMM: BM=256 BN=128 BK=32, ring-3, 72 KB ======
// 8 waves as 4M x 2N, per-wave 64x64 (acc 4x4). Slot (24 KB = 12288 shorts):
//   A @ 0: [nb16][kg4][fr16][8] (8192 sh); B @ 8192: [nb8][kg4][fr16][8].
// 3 gloads/thread/tile; ring-3; one raw barrier + vmcnt(3) per K-step.
// 72 KB LDS -> 2 blocks/CU: cross-block LDS-read/MFMA overlap (m114).

__device__ inline void stage_p(const unsigned short* pa, const unsigned short* pb,
                               int ko, unsigned short* slot, int wave)
{
  gload_lds16(pa + ko,            slot + wave*512);
  gload_lds16(pa + 128*1024 + ko, slot + (wave+8)*512);
  gload_lds16(pb + ko,            slot + 8192 + wave*512);
}

__global__ __launch_bounds__(512, 2) void k_proj(
    const unsigned short* __restrict__ Xq, const unsigned short* __restrict__ Xv,
    const unsigned short* __restrict__ Mt, const unsigned short* __restrict__ WvT,
    unsigned short* __restrict__ qm, unsigned short* __restrict__ vT)
{
  __shared__ __align__(16) unsigned short smem[36864];     // 72 KB: 3 x 24 KB
  int z = blockIdx.z;
  const unsigned short* X  = z==0 ? Xq : Xv;
  const unsigned short* Wt = z==0 ? Mt : WvT;
  // 256 blocks/z = 32 M-tiles x 8 N-tiles; XCD-chunked swizzle (256%8==0)
  int bid = blockIdx.x;
  int t8  = (bid & 7)*32 + (bid >> 3);
  int mt  = t8 >> 3, nt = t8 & 7;
  int m0 = mt*256, n0 = nt*128;
  int tid = threadIdx.x, wave = tid >> 6, lane = tid & 63;
  int wr = wave >> 1, wc = wave & 1;                       // 4M x 2N
  int fr = lane & 15, kg = lane >> 4;
  int frkg = kg*128 + fr*8;

  const unsigned short* pa = X  + (size_t)(m0 + wave*16 + fr)*1024 + kg*8;
  const unsigned short* pb = Wt + (size_t)(n0 + wave*16 + fr)*1024 + kg*8;

  f32x4 acc[4][4] = {};

  stage_p(pa, pb, 0,  smem,         wave);
  stage_p(pa, pb, 32, smem + 12288, wave);
  for (int kt = 0; kt < 32; ++kt){
    if (kt < 31) asm volatile("s_waitcnt vmcnt(3)\n\ts_barrier" ::: "memory");
    else         asm volatile("s_waitcnt vmcnt(0)\n\ts_barrier" ::: "memory");
    const unsigned short* As = smem + (unsigned)(kt % 3) * 12288;
    const unsigned short* Bs = As + 8192;
    bf16x8 av[4], bv[4];
    #pragma unroll
    for (int mi = 0; mi < 4; ++mi)
      av[mi] = *(const bf16x8*)(As + (wr*4 + mi)*512 + frkg);
    #pragma unroll
    for (int ni = 0; ni < 4; ++ni)
      bv[ni] = *(const bf16x8*)(Bs + (wc*4 + ni)*512 + frkg);
    #pragma unroll
    for (int mi = 0; mi < 4; ++mi)
      #pragma unroll
      for (int ni = 0; ni < 4; ++ni)
        acc[mi][ni] = __builtin_amdgcn_mfma_f32_16x16x32_bf16(av[mi], bv[ni], acc[mi][ni], 0, 0, 0);
    if (kt + 2 < 32)
      stage_p(pa, pb, (kt+2)*32, smem + (unsigned)((kt+2) % 3) * 12288, wave);
  }

  if (z == 0){
    #pragma unroll
    for (int mi = 0; mi < 4; ++mi)
      #pragma unroll
      for (int ni = 0; ni < 4; ++ni){
        int r = m0 + wr*64 + mi*16 + kg*4;
        int c = n0 + wc*64 + ni*16 + fr;
        #pragma unroll
        for (int i = 0; i < 4; ++i)
          qm[(size_t)(r+i)*DM + c] = f2bf(acc[mi][ni][i]);
      }
  } else {
    __syncthreads();                                  // pipeline drained; reuse smem
    unsigned short* Tt = smem;                        // [128 d][264] transposed tile
    #pragma unroll
    for (int mi = 0; mi < 4; ++mi)
      #pragma unroll
      for (int ni = 0; ni < 4; ++ni){
        int d2 = wc*64 + ni*16 + fr;                  // 0..127
        int l  = wr*64 + mi*16 + kg*4;                // 0..255
        u16x4 t;
        t[0]=f2bf(acc[mi][ni][0]); t[1]=f2bf(acc[mi][ni][1]);
        t[2]=f2bf(acc[mi][ni][2]); t[3]=f2bf(acc[mi][ni][3]);
        *(u16x4*)(Tt + d2*264 + l) = t;
      }
    __syncthreads();
    int b = m0 >> 10, l0 = m0 & 1023;
    int row = tid >> 2, ch = tid & 3;                 // 128 rows x 4 chunks of 64 shorts
    unsigned short* dst = vT + ((size_t)b << 20) + (size_t)(n0 + row)*LSEQ + l0 + ch*64;
    const unsigned short* srcT = Tt + row*264 + ch*64;
    #pragma unroll
    for (int k = 0; k < 8; ++k)
      *(u16x8*)(dst + k*8) = *(const u16x8*)(srcT + k*8);
  }
}

// ---------------- scores: S = bf16((qm . Xk)/32), causal block-skip ---------
__global__ __launch_bounds__(256) void k_scores(
    const unsigned short* __restrict__ q, const unsigned short* __restrict__ k,
    unsigned short* __restrict__ S)
{
  __shared__ __align__(16) unsigned short smem[24576];
  int b = blockIdx.z;
  int raw = blockIdx.x + 8*blockIdx.y;
  int tile = (raw & 7)*8 + (raw >> 3);
  int kt = tile & 7, qt = tile >> 3;
  if (kt > qt) return;                               // block-uniform exit
  const unsigned short* qb = q + ((size_t)b << 20);
  const unsigned short* kb = k + ((size_t)b << 20);
  int m0 = qt*128, n0 = kt*128;
  int tid = threadIdx.x, wave = tid >> 6, lane = tid & 63;
  int wrb4 = (wave >> 1)*4, wcb4 = (wave & 1)*4, fr = lane & 15, kg = lane >> 4;
  f32x4 acc[4][4] = {};
  gemm_ring(qb, m0, kb, n0, smem, 32, wave, lane, wrb4, wcb4, fr, kg, acc);

  unsigned short* Sb = S + ((size_t)b << 20);
  const float scale = 0.03125f;                      // 1/sqrt(1024)
  #pragma unroll
  for (int mi = 0; mi < 4; ++mi)
    #pragma unroll
    for (int ni = 0; ni < 4; ++ni){
      int r = m0 + wrb4*16 + mi*16 + kg*4;
      int c = n0 + wcb4*16 + ni*16 + fr;
      #pragma unroll
      for (int i = 0; i < 4; ++i)
        Sb[(size_t)(r+i)*LSEQ + c] = f2bf(acc[mi][ni][i] * scale);
    }
}

// ---------------- causal row softmax: one WAVE per row, no barriers ---------
__global__ __launch_bounds__(256) void k_softmax(
    const unsigned short* __restrict__ S, unsigned short* __restrict__ P)
{
  int tid = threadIdx.x;
  int row = blockIdx.x*4 + (tid >> 6);                // 0..8191, wave-uniform
  int lane = tid & 63;
  int qq = row & 1023;
  const unsigned short* srow = S + (size_t)row * 1024;
  unsigned short* prow = P + (size_t)row * 1024;

  u16x8 h0 = *(const u16x8*)(srow + lane*16);
  u16x8 h1 = *(const u16x8*)(srow + lane*16 + 8);
  float v[16];
  float m = -1e30f;
  #pragma unroll
  for (int e = 0; e < 8; ++e){
    int i0 = lane*16 + e, i1 = lane*16 + 8 + e;
    v[e]   = (i0 <= qq) ? bf2f(h0[e]) : -1e30f;
    v[8+e] = (i1 <= qq) ? bf2f(h1[e]) : -1e30f;
  }
  #pragma unroll
  for (int e = 0; e < 16; ++e) m = fmaxf(m, v[e]);
  #pragma unroll
  for (int off = 32; off >= 1; off >>= 1) m = fmaxf(m, __shfl_xor(m, off));

  float s = 0.f;
  float e16[16];
  #pragma unroll
  for (int e = 0; e < 16; ++e){
    e16[e] = (v[e] > -1e29f) ? __expf(v[e] - m) : 0.f;
    s += e16[e];
  }
  #pragma unroll
  for (int off = 32; off >= 1; off >>= 1) s += __shfl_xor(s, off);
  float inv = 1.f / s;

  u16x8 o0, o1;
  #pragma unroll
  for (int e = 0; e < 8; ++e){
    o0[e] = f2bf(e16[e] * inv);
    o1[e] = f2bf(e16[8+e] * inv);
  }
  *(u16x8*)(prow + lane*16)     = o0;
  *(u16x8*)(prow + lane*16 + 8) = o1;
}

// ---------------- PV: O = P @ vT^T, diag-cut K, longest-first ---------------
__global__ __launch_bounds__(256) void k_pv(
    const unsigned short* __restrict__ P, const unsigned short* __restrict__ vT,
    float* __restrict__ O)
{
  __shared__ __align__(16) unsigned short smem[24576];
  int b = blockIdx.z;
  int raw = blockIdx.x + 8*blockIdx.y;
  int qt = 7 - (raw & 7);                             // longest-K blocks dispatch first
  int dt = raw >> 3;
  const unsigned short* Pb = P  + ((size_t)b << 20);
  const unsigned short* Vb = vT + ((size_t)b << 20);
  int m0 = qt*128, n0 = dt*128;
  int tid = threadIdx.x, wave = tid >> 6, lane = tid & 63;
  int wrb4 = (wave >> 1)*4, wcb4 = (wave & 1)*4, fr = lane & 15, kg = lane >> 4;
  f32x4 acc[4][4] = {};
  int nk = (qt + 1) * 4;                              // kk in [0,(qt+1)*128); >= 4
  gemm_ring(Pb, m0, Vb, n0, smem, nk, wave, lane, wrb4, wcb4, fr, kg, acc);

  float* Ob = O + ((size_t)(b*1024 + m0) << 10);
  #pragma unroll
  for (int mi = 0; mi < 4; ++mi)
    #pragma unroll
    for (int ni = 0; ni < 4; ++ni){
      int r = wrb4*16 + mi*16 + kg*4;
      int c = n0 + wcb4*16 + ni*16 + fr;
      #pragma unroll
      for (int i = 0; i < 4; ++i)
        Ob[(size_t)(r+i)*DM + c] = acc[mi][ni][i];
    }
}

extern "C" void kernel_launch(void* const* d_in, const int* in_sizes, int n_in,
                              void* d_out, int out_size, void* d_ws, size_t ws_size,
                              hipStream_t stream)
{
  const float* query = (const float*)d_in[0];
  const float* key   = (const float*)d_in[1];
  const float* value = (const float*)d_in[2];
  const float* Wq    = (const float*)d_in[3];
  const float* Wk    = (const float*)d_in[4];
  const float* Wv    = (const float*)d_in[5];
  float* out = (float*)d_out;

  // ws layout (shorts), 70 MB total — proven footprint:
  unsigned short* ws = (unsigned short*)d_ws;
  unsigned short* qm   = ws;                                  // 8M  (Xq @ WqWk^T)
  unsigned short* vT   = qm   + (size_t)MROWS*DM;             // 8M  [B][D][L]
  unsigned short* Xk   = vT   + (size_t)MROWS*DM;             // 8M  bf16 key input
  unsigned short* PXv  = Xk   + (size_t)MROWS*DM;             // 8M  Xv, later P
  unsigned short* Wqbf = PXv  + (size_t)MROWS*DM;             // 1M
  unsigned short* Wkbf = Wqbf + (size_t)DM*DM;                // 1M
  unsigned short* WvT  = Wkbf + (size_t)DM*DM;                // 1M

  // d_out dead-buffer reuse (32 MB): Xq + Mt live until k_proj is done;
  // S bf16 then overlaps the dead Xq region; k_pv overwrites all of d_out.
  unsigned short* outU = (unsigned short*)d_out;
  unsigned short* Xq = outU;                                  // 8M shorts
  unsigned short* Mt = outU + (size_t)MROWS*DM;               // 1M shorts
  unsigned short* S  = outU;                                  // bf16 scores (Xq dead)

  dim3 blk(256);
  k_prep   <<<dim3(13568), blk, 0, stream>>>(query, key, value, Wq, Wk, Wv,
                                             Xq, Xk, PXv, Wqbf, Wkbf, WvT);
  k_mt     <<<dim3(8,8,1),  blk, 0, stream>>>(Wkbf, Wqbf, Mt);
  k_proj   <<<dim3(256,1,2), dim3(512), 0, stream>>>(Xq, PXv, Mt, WvT, qm, vT);
  k_scores <<<dim3(8,8,8),  blk, 0, stream>>>(qm, Xk, S);
  k_softmax<<<dim3(2048),   blk, 0, stream>>>(S, PXv);
  k_pv     <<<dim3(8,8,8),  blk, 0, stream>>>(PXv, vT, out);
}

// Round 15
// 168.101 us; speedup vs baseline: 1.1170x; 1.0695x over previous
//
#include <hip/hip_runtime.h>

#define DM   1024
#define LSEQ 1024
#define BATCH 8
#define MROWS (BATCH*LSEQ)   // 8192

typedef __attribute__((ext_vector_type(8))) short  bf16x8;
typedef __attribute__((ext_vector_type(4))) float  f32x4;
typedef __attribute__((ext_vector_type(4))) unsigned short u16x4;
typedef __attribute__((ext_vector_type(8))) unsigned short u16x8;

__device__ inline unsigned short f2bf(float f){
  unsigned u = __builtin_bit_cast(unsigned, f);
  u += 0x7fffu + ((u >> 16) & 1u);          // RNE
  return (unsigned short)(u >> 16);
}
__device__ inline float bf2f(unsigned short h){
  unsigned u = (unsigned)h << 16;
  return __builtin_bit_cast(float, u);
}

__device__ inline void gload_lds16(const void* g, void* l){
  __builtin_amdgcn_global_load_lds(
      (const __attribute__((address_space(1))) void*)g,
      (__attribute__((address_space(3))) void*)l,
      16, 0, 0);
}

// ================= 128x32-tile helpers (k_mt only — proven path) ============
__device__ inline void stage_gload(const unsigned short* src, int row0, int k0,
                                   unsigned short* lds, int wave, int lane)
{
  int fr = lane & 15, kg = lane >> 4;
  #pragma unroll
  for (int it = 0; it < 2; ++it){
    int nb = it*4 + wave;                 // wave-uniform
    gload_lds16(src + (size_t)(row0 + nb*16 + fr)*1024 + k0 + kg*8,
                lds + nb*512);
  }
}

__device__ inline void mma_step(const unsigned short* As, const unsigned short* Bs,
                                int wrb4, int wcb4, int fr, int kg,
                                f32x4 acc[4][4])
{
  bf16x8 av[4], bv[4];
  #pragma unroll
  for (int mi = 0; mi < 4; ++mi)
    av[mi] = *(const bf16x8*)(As + (size_t)(((wrb4 + mi)*4 + kg)*16 + fr)*8);
  #pragma unroll
  for (int ni = 0; ni < 4; ++ni)
    bv[ni] = *(const bf16x8*)(Bs + (size_t)(((wcb4 + ni)*4 + kg)*16 + fr)*8);
  #pragma unroll
  for (int mi = 0; mi < 4; ++mi)
    #pragma unroll
    for (int ni = 0; ni < 4; ++ni)
      acc[mi][ni] = __builtin_amdgcn_mfma_f32_16x16x32_bf16(av[mi], bv[ni], acc[mi][ni], 0, 0, 0);
}

// depth-3 ring (R4, proven): ONE raw barrier per K-step, counted vmcnt.
__device__ inline void gemm_ring(const unsigned short* __restrict__ A, int m0,
                                 const unsigned short* __restrict__ B, int n0,
                                 unsigned short* smem, int nk,
                                 int wave, int lane,
                                 int wrb4, int wcb4, int fr, int kg,
                                 f32x4 acc[4][4])
{
  stage_gload(A, m0, 0,  smem,        wave, lane);
  stage_gload(B, n0, 0,  smem + 4096, wave, lane);
  stage_gload(A, m0, 32, smem + 8192, wave, lane);
  stage_gload(B, n0, 32, smem + 8192 + 4096, wave, lane);
  for (int kt = 0; kt < nk; ++kt){
    if (kt + 1 < nk) asm volatile("s_waitcnt vmcnt(4)\n\ts_barrier" ::: "memory");
    else             asm volatile("s_waitcnt vmcnt(0)\n\ts_barrier" ::: "memory");
    unsigned short* buf = smem + (unsigned)(kt % 3) * 8192;
    mma_step(buf, buf + 4096, wrb4, wcb4, fr, kg, acc);
    if (kt + 2 < nk){
      unsigned short* nb = smem + (unsigned)((kt + 2) % 3) * 8192;
      stage_gload(A, m0, (kt+2)*32, nb,        wave, lane);
      stage_gload(B, n0, (kt+2)*32, nb + 4096, wave, lane);
    }
  }
}

// ---------------- prep: all fp32->bf16 conversions in ONE launch ------------
__global__ __launch_bounds__(256) void k_prep(
    const float* __restrict__ query, const float* __restrict__ key, const float* __restrict__ value,
    const float* __restrict__ Wq, const float* __restrict__ Wk, const float* __restrict__ Wv,
    unsigned short* __restrict__ Xq, unsigned short* __restrict__ Xk, unsigned short* __restrict__ Xv,
    unsigned short* __restrict__ Wqbf, unsigned short* __restrict__ Wkbf,
    unsigned short* __restrict__ WvT)
{
  int bid = blockIdx.x;
  int tid = threadIdx.x;
  if (bid < 12288){
    int z = bid >> 12, ib = bid & 4095;
    const float* X = z==0 ? query : (z==1 ? key : value);
    unsigned short* Y = z==0 ? Xq : (z==1 ? Xk : Xv);
    size_t i = ((size_t)ib*256 + tid)*8;
    f32x4 a = *(const f32x4*)(X+i);
    f32x4 b = *(const f32x4*)(X+i+4);
    u16x8 o;
    o[0]=f2bf(a[0]); o[1]=f2bf(a[1]); o[2]=f2bf(a[2]); o[3]=f2bf(a[3]);
    o[4]=f2bf(b[0]); o[5]=f2bf(b[1]); o[6]=f2bf(b[2]); o[7]=f2bf(b[3]);
    *(u16x8*)(Y+i) = o;
  } else if (bid < 13312){
    int b2 = bid - 12288;
    int z = b2 >> 9, ib = b2 & 511;
    const float* X = z==0 ? Wq : Wk;
    unsigned short* Y = z==0 ? Wqbf : Wkbf;
    size_t i = ((size_t)ib*256 + tid)*8;
    f32x4 a = *(const f32x4*)(X+i);
    f32x4 b = *(const f32x4*)(X+i+4);
    u16x8 o;
    o[0]=f2bf(a[0]); o[1]=f2bf(a[1]); o[2]=f2bf(a[2]); o[3]=f2bf(a[3]);
    o[4]=f2bf(b[0]); o[5]=f2bf(b[1]); o[6]=f2bf(b[2]); o[7]=f2bf(b[3]);
    *(u16x8*)(Y+i) = o;
  } else {
    __shared__ unsigned short tile[64*68];
    int b2 = bid - 13312;
    int n0 = (b2 & 15)*64, k0 = (b2 >> 4)*64;
    {
      int r = tid >> 4;                 // 0..15
      int c = (tid & 15) * 4;
      #pragma unroll
      for (int it = 0; it < 4; ++it){
        f32x4 v = *(const f32x4*)(Wv + (size_t)(k0 + it*16 + r)*DM + n0 + c);
        u16x4 h; h[0]=f2bf(v[0]); h[1]=f2bf(v[1]); h[2]=f2bf(v[2]); h[3]=f2bf(v[3]);
        *(u16x4*)(tile + (it*16 + r)*68 + c) = h;
      }
    }
    __syncthreads();
    {
      int nl = tid >> 2;                // 0..63
      int kc = (tid & 3) * 16;
      u16x8 o;
      #pragma unroll
      for (int j = 0; j < 8; ++j) o[j] = tile[(kc+j)*68 + nl];
      *(u16x8*)(WvT + (size_t)(n0+nl)*DM + k0 + kc) = o;
      #pragma unroll
      for (int j = 0; j < 8; ++j) o[j] = tile[(kc+8+j)*68 + nl];
      *(u16x8*)(WvT + (size_t)(n0+nl)*DM + k0 + kc + 8) = o;
    }
  }
}

// ---------------- Mt[c][d] = bf16( sum_e Wk[c][e] * Wq[d][e] ) --------------
__global__ __launch_bounds__(256) void k_mt(
    const unsigned short* __restrict__ Wkbf, const unsigned short* __restrict__ Wqbf,
    unsigned short* __restrict__ Mt)
{
  __shared__ __align__(16) unsigned short smem[24576];
  int m0 = blockIdx.y*128, n0 = blockIdx.x*128;
  int tid = threadIdx.x, wave = tid >> 6, lane = tid & 63;
  int wrb4 = (wave >> 1)*4, wcb4 = (wave & 1)*4, fr = lane & 15, kg = lane >> 4;
  f32x4 acc[4][4] = {};
  gemm_ring(Wkbf, m0, Wqbf, n0, smem, 32, wave, lane, wrb4, wcb4, fr, kg, acc);
  #pragma unroll
  for (int mi = 0; mi < 4; ++mi)
    #pragma unroll
    for (int ni = 0; ni < 4; ++ni){
      int r = m0 + wrb4*16 + mi*16 + kg*4;
      int c = n0 + wcb4*16 + ni*16 + fr;
      #pragma unroll
      for (int i = 0; i < 4; ++i)
        Mt[(size_t)(r+i)*DM + c] = f2bf(acc[mi][ni][i]);
    }
}

// ================= 256x128 big-tile core (BK=64, 8 waves 4Mx2N, 96KB dbuf) ==
// R12-proven phase structure, generalized to runtime nk (K-tiles of 64).
// buf b at smem + b*24576 (shorts): A chunks idx*512 (idx=s*16+nb, 0..31),
// B chunks 16384+idx*512 (idx=s*8+nb, 0..15). Per phase: vmcnt(6)+barrier ->
// ds_read frags -> lgkm(0)+barrier -> stage tile t+2 (same parity buf) -> MFMA.

#define BWB6 asm volatile("s_waitcnt vmcnt(6)\n\ts_barrier" ::: "memory")
#define BWB0 asm volatile("s_waitcnt vmcnt(0)\n\ts_barrier" ::: "memory")
#define BLB  asm volatile("s_waitcnt lgkmcnt(0)\n\ts_barrier" ::: "memory")

#define BSTAGE(CB, KOF) do{ \
  _Pragma("unroll") for (int i_=0;i_<4;++i_) \
    gload_lds16(pa[i_] + (KOF), smem + (CB) + (wave+8*i_)*512); \
  _Pragma("unroll") for (int i_=0;i_<2;++i_) \
    gload_lds16(pb[i_] + (KOF), smem + (CB) + 16384 + (wave+8*i_)*512); }while(0)

__device__ inline void gemm_big(const unsigned short* __restrict__ A, int m0,
                                const unsigned short* __restrict__ B, int n0,
                                unsigned short* smem, int nk,
                                int wave, int lane, f32x4 acc[4][4])
{
  int wr = wave >> 1, wc = wave & 1;
  int fr = lane & 15, kg = lane >> 4;
  int wr4 = wr*4, wc4 = wc*4, lane8 = lane*8;

  const unsigned short* pa[4];
  const unsigned short* pb[2];
  #pragma unroll
  for (int i = 0; i < 4; ++i){
    int idx = wave + 8*i, s = idx >> 4, nb = idx & 15;
    pa[i] = A + (size_t)(m0 + nb*16 + fr)*1024 + s*32 + kg*8;
  }
  #pragma unroll
  for (int i = 0; i < 2; ++i){
    int idx = wave + 8*i, s = idx >> 3, nb = idx & 7;
    pb[i] = B + (size_t)(n0 + nb*16 + fr)*1024 + s*32 + kg*8;
  }

  BSTAGE(0, 0);                                  // tile 0 -> buf0
  BSTAGE(24576, 64);                             // tile 1 -> buf1

  #pragma unroll 2
  for (int t = 0; t < nk; ++t){
    if (t + 1 < nk) BWB6; else BWB0;
    unsigned cb = (unsigned)(t & 1) * 24576;
    bf16x8 av[2][4], bv[2][4];
    #pragma unroll
    for (int s_ = 0; s_ < 2; ++s_){
      #pragma unroll
      for (int i_ = 0; i_ < 4; ++i_)
        av[s_][i_] = *(const bf16x8*)(smem + cb + s_*8192 + (wr4+i_)*512 + lane8);
      #pragma unroll
      for (int i_ = 0; i_ < 4; ++i_)
        bv[s_][i_] = *(const bf16x8*)(smem + cb + 16384 + s_*4096 + (wc4+i_)*512 + lane8);
    }
    BLB;
    if (t + 2 < nk) BSTAGE(cb, (t+2)*64);
    #pragma unroll
    for (int s_ = 0; s_ < 2; ++s_)
      #pragma unroll
      for (int mi = 0; mi < 4; ++mi)
        #pragma unroll
        for (int ni = 0; ni < 4; ++ni)
          acc[mi][ni] = __builtin_amdgcn_mfma_f32_16x16x32_bf16(av[s_][mi], bv[s_][ni], acc[mi][ni], 0, 0, 0);
  }
}

// ================= projection GEMM (R12-proven, unchanged) ==================
#define WB6 asm volatile("s_waitcnt vmcnt(6)\n\ts_barrier" ::: "memory")
#define WB0 asm volatile("s_waitcnt vmcnt(0)\n\ts_barrier" ::: "memory")
#define LB  asm volatile("s_waitcnt lgkmcnt(0)\n\ts_barrier" ::: "memory")

#define STAGEALL(AB, BB, KOF) do{ \
  _Pragma("unroll") for (int i_=0;i_<4;++i_) gload_lds16(pa[i_] + (KOF), smem + (AB) + (wave+8*i_)*512); \
  _Pragma("unroll") for (int i_=0;i_<2;++i_) gload_lds16(pb[i_] + (KOF), smem + (BB) + (wave+8*i_)*512); }while(0)

#define PHASEBODY(AB, BB, KOF, DOSTAGE, WAITM) do{ \
  WAITM; \
  bf16x8 av[2][4], bv[2][4]; \
  _Pragma("unroll") for (int s_=0;s_<2;++s_){ \
    _Pragma("unroll") for (int i_=0;i_<4;++i_) \
      av[s_][i_] = *(const bf16x8*)(smem + (AB) + s_*8192 + (wr4+i_)*512 + lane8); \
    _Pragma("unroll") for (int i_=0;i_<4;++i_) \
      bv[s_][i_] = *(const bf16x8*)(smem + (BB) + s_*4096 + (wc4+i_)*512 + lane8); \
  } \
  LB; \
  if (DOSTAGE){ \
    _Pragma("unroll") for (int i_=0;i_<4;++i_) gload_lds16(pa[i_] + (KOF), smem + (AB) + (wave+8*i_)*512); \
    _Pragma("unroll") for (int i_=0;i_<2;++i_) gload_lds16(pb[i_] + (KOF), smem + (BB) + (wave+8*i_)*512); \
  } \
  _Pragma("unroll") for (int s_=0;s_<2;++s_) \
    _Pragma("unroll") for (int mi_=0;mi_<4;++mi_) \
      _Pragma("unroll") for (int ni_=0;ni_<4;++ni_) \
        acc[mi_][ni_] = __builtin_amdgcn_mfma_f32_16x16x32_bf16(av[s_][mi_], bv[s_][ni_], acc[mi_][ni_], 0,0,0); \
}while(0)

__global__ __launch_bounds__(512, 2) void k_proj(
    const unsigned short* __restrict__ Xq, const unsigned short* __restrict__ Xv,
    const unsigned short* __restrict__ Mt, const unsigned short* __restrict__ WvT,
    unsigned short* __restrict__ qm, unsigned short* __restrict__ vT)
{
  __shared__ __align__(16) unsigned short smem[49152];     // 96 KB
  int z = blockIdx.z;
  const unsigned short* X  = z==0 ? Xq : Xv;
  const unsigned short* Wt = z==0 ? Mt : WvT;
  int bid = blockIdx.x;
  int t8  = (bid & 7)*32 + (bid >> 3);
  int mt  = t8 >> 3, nt = t8 & 7;
  int m0 = mt*256, n0 = nt*128;
  int tid = threadIdx.x, wave = tid >> 6, lane = tid & 63;
  int wr = wave >> 1, wc = wave & 1;
  int fr = lane & 15, kg = lane >> 4;
  int wr4 = wr*4, wc4 = wc*4, lane8 = lane*8;

  const unsigned short* pa[4];
  const unsigned short* pb[2];
  #pragma unroll
  for (int i = 0; i < 4; ++i){
    int idx = wave + 8*i, s = idx >> 4, nb = idx & 15;
    pa[i] = X + (size_t)(m0 + nb*16 + fr)*1024 + s*32 + kg*8;
  }
  #pragma unroll
  for (int i = 0; i < 2; ++i){
    int idx = wave + 8*i, s = idx >> 3, nb = idx & 7;
    pb[i] = Wt + (size_t)(n0 + nb*16 + fr)*1024 + s*32 + kg*8;
  }

  f32x4 acc[4][4] = {};

  STAGEALL(0,     16384, 0);        // tile 0 -> buf0
  STAGEALL(24576, 40960, 64);       // tile 1 -> buf1
  #pragma unroll
  for (int g = 0; g < 7; ++g){
    PHASEBODY(0,     16384, (2*g+2)*64, true, WB6);
    PHASEBODY(24576, 40960, (2*g+3)*64, true, WB6);
  }
  PHASEBODY(0,     16384, 0, false, WB6);
  PHASEBODY(24576, 40960, 0, false, WB0);

  if (z == 0){
    #pragma unroll
    for (int mi = 0; mi < 4; ++mi)
      #pragma unroll
      for (int ni = 0; ni < 4; ++ni){
        int r = m0 + wr*64 + mi*16 + kg*4;
        int c = n0 + wc*64 + ni*16 + fr;
        #pragma unroll
        for (int i = 0; i < 4; ++i)
          qm[(size_t)(r+i)*DM + c] = f2bf(acc[mi][ni][i]);
      }
  } else {
    __syncthreads();
    unsigned short* Tt = smem;                        // [128 d][264]
    #pragma unroll
    for (int mi = 0; mi < 4; ++mi)
      #pragma unroll
      for (int ni = 0; ni < 4; ++ni){
        int d2 = wc*64 + ni*16 + fr;
        int l  = wr*64 + mi*16 + kg*4;
        u16x4 t;
        t[0]=f2bf(acc[mi][ni][0]); t[1]=f2bf(acc[mi][ni][1]);
        t[2]=f2bf(acc[mi][ni][2]); t[3]=f2bf(acc[mi][ni][3]);
        *(u16x4*)(Tt + d2*264 + l) = t;
      }
    __syncthreads();
    int b = m0 >> 10, l0 = m0 & 1023;
    int row = tid >> 2, ch = tid & 3;
    unsigned short* dst = vT + ((size_t)b << 20) + (size_t)(n0 + row)*LSEQ + l0 + ch*64;
    const unsigned short* srcT = Tt + row*264 + ch*64;
    #pragma unroll
    for (int k = 0; k < 8; ++k)
      *(u16x8*)(dst + k*8) = *(const u16x8*)(srcT + k*8);
  }
}

// ---------------- scores: S = bf16((qm . Xk)/32), 256x128 tiles -------------
__global__ __launch_bounds__(512, 2) void k_scores(
    const unsigned short* __restrict__ q, const unsigned short* __restrict__ k,
    unsigned short* __restrict__ S)
{
  __shared__ __align__(16) unsigned short smem[49152];
  int b = blockIdx.z;
  int raw = blockIdx.x;
  int t8 = (raw & 7)*4 + (raw >> 3);                 // XCD-chunked (32%8==0)
  int qt = t8 >> 3, kt = t8 & 7;
  if (kt > 2*qt + 1) return;                         // strictly above diagonal
  const unsigned short* qb = q + ((size_t)b << 20);
  const unsigned short* kb = k + ((size_t)b << 20);
  int m0 = qt*256, n0 = kt*128;
  int tid = threadIdx.x, wave = tid >> 6, lane = tid & 63;
  int wr = wave >> 1, wc = wave & 1, fr = lane & 15, kg = lane >> 4;

  f32x4 acc[4][4] = {};
  gemm_big(qb, m0, kb, n0, smem, 16, wave, lane, acc);

  unsigned short* Sb = S + ((size_t)b << 20);
  const float scale = 0.03125f;                      // 1/sqrt(1024)
  #pragma unroll
  for (int mi = 0; mi < 4; ++mi)
    #pragma unroll
    for (int ni = 0; ni < 4; ++ni){
      int r = m0 + wr*64 + mi*16 + kg*4;
      int c = n0 + wc*64 + ni*16 + fr;
      #pragma unroll
      for (int i = 0; i < 4; ++i)
        Sb[(size_t)(r+i)*LSEQ + c] = f2bf(acc[mi][ni][i] * scale);
    }
}

// ---------------- causal row softmax: one WAVE per row, no barriers ---------
__global__ __launch_bounds__(256) void k_softmax(
    const unsigned short* __restrict__ S, unsigned short* __restrict__ P)
{
  int tid = threadIdx.x;
  int row = blockIdx.x*4 + (tid >> 6);                // 0..8191, wave-uniform
  int lane = tid & 63;
  int qq = row & 1023;
  const unsigned short* srow = S + (size_t)row * 1024;
  unsigned short* prow = P + (size_t)row * 1024;

  u16x8 h0 = *(const u16x8*)(srow + lane*16);
  u16x8 h1 = *(const u16x8*)(srow + lane*16 + 8);
  float v[16];
  float m = -1e30f;
  #pragma unroll
  for (int e = 0; e < 8; ++e){
    int i0 = lane*16 + e, i1 = lane*16 + 8 + e;
    v[e]   = (i0 <= qq) ? bf2f(h0[e]) : -1e30f;
    v[8+e] = (i1 <= qq) ? bf2f(h1[e]) : -1e30f;
  }
  #pragma unroll
  for (int e = 0; e < 16; ++e) m = fmaxf(m, v[e]);
  #pragma unroll
  for (int off = 32; off >= 1; off >>= 1) m = fmaxf(m, __shfl_xor(m, off));

  float s = 0.f;
  float e16[16];
  #pragma unroll
  for (int e = 0; e < 16; ++e){
    e16[e] = (v[e] > -1e29f) ? __expf(v[e] - m) : 0.f;
    s += e16[e];
  }
  #pragma unroll
  for (int off = 32; off >= 1; off >>= 1) s += __shfl_xor(s, off);
  float inv = 1.f / s;

  u16x8 o0, o1;
  #pragma unroll
  for (int e = 0; e < 8; ++e){
    o0[e] = f2bf(e16[e] * inv);
    o1[e] = f2bf(e16[8+e] * inv);
  }
  *(u16x8*)(prow + lane*16)     = o0;
  *(u16x8*)(prow + lane*16 + 8) = o1;
}

// ---------------- PV: O = P @ vT^T, 256x128 tiles, diag-cut K ---------------
__global__ __launch_bounds__(512, 2) void k_pv(
    const unsigned short* __restrict__ P, const unsigned short* __restrict__ vT,
    float* __restrict__ O)
{
  __shared__ __align__(16) unsigned short smem[49152];
  int b = blockIdx.z;
  int raw = blockIdx.x;
  int t8 = (raw & 7)*4 + (raw >> 3);                 // XCD-chunked
  int qt = 3 - (t8 & 3), dt = t8 >> 2;               // longest-K first
  const unsigned short* Pb = P  + ((size_t)b << 20);
  const unsigned short* Vb = vT + ((size_t)b << 20);
  int m0 = qt*256, n0 = dt*128;
  int tid = threadIdx.x, wave = tid >> 6, lane = tid & 63;
  int wr = wave >> 1, wc = wave & 1, fr = lane & 15, kg = lane >> 4;

  f32x4 acc[4][4] = {};
  int nk = (qt + 1) * 4;                             // K-tiles of 64; 4..16
  gemm_big(Pb, m0, Vb, n0, smem, nk, wave, lane, acc);

  float* Ob = O + ((size_t)(b*1024 + m0) << 10);
  #pragma unroll
  for (int mi = 0; mi < 4; ++mi)
    #pragma unroll
    for (int ni = 0; ni < 4; ++ni){
      int r = wr*64 + mi*16 + kg*4;
      int c = n0 + wc*64 + ni*16 + fr;
      #pragma unroll
      for (int i = 0; i < 4; ++i)
        Ob[(size_t)(r+i)*DM + c] = acc[mi][ni][i];
    }
}

extern "C" void kernel_launch(void* const* d_in, const int* in_sizes, int n_in,
                              void* d_out, int out_size, void* d_ws, size_t ws_size,
                              hipStream_t stream)
{
  const float* query = (const float*)d_in[0];
  const float* key   = (const float*)d_in[1];
  const float* value = (const float*)d_in[2];
  const float* Wq    = (const float*)d_in[3];
  const float* Wk    = (const float*)d_in[4];
  const float* Wv    = (const float*)d_in[5];
  float* out = (float*)d_out;

  // ws layout (shorts), 70 MB total — proven footprint:
  unsigned short* ws = (unsigned short*)d_ws;
  unsigned short* qm   = ws;                                  // 8M  (Xq @ WqWk^T)
  unsigned short* vT   = qm   + (size_t)MROWS*DM;             // 8M  [B][D][L]
  unsigned short* Xk   = vT   + (size_t)MROWS*DM;             // 8M  bf16 key input
  unsigned short* PXv  = Xk   + (size_t)MROWS*DM;             // 8M  Xv, later P
  unsigned short* Wqbf = PXv  + (size_t)MROWS*DM;             // 1M
  unsigned short* Wkbf = Wqbf + (size_t)DM*DM;                // 1M
  unsigned short* WvT  = Wkbf + (size_t)DM*DM;                // 1M

  // d_out dead-buffer reuse (32 MB): Xq + Mt live until k_proj is done;
  // S bf16 then overlaps the dead Xq region; k_pv overwrites all of d_out.
  unsigned short* outU = (unsigned short*)d_out;
  unsigned short* Xq = outU;                                  // 8M shorts
  unsigned short* Mt = outU + (size_t)MROWS*DM;               // 1M shorts
  unsigned short* S  = outU;                                  // bf16 scores (Xq dead)

  dim3 blk(256);
  k_prep   <<<dim3(13568), blk, 0, stream>>>(query, key, value, Wq, Wk, Wv,
                                             Xq, Xk, PXv, Wqbf, Wkbf, WvT);
  k_mt     <<<dim3(8,8,1),  blk, 0, stream>>>(Wkbf, Wqbf, Mt);
  k_proj   <<<dim3(256,1,2), dim3(512), 0, stream>>>(Xq, PXv, Mt, WvT, qm, vT);
  k_scores <<<dim3(32,1,8), dim3(512), 0, stream>>>(qm, Xk, S);
  k_softmax<<<dim3(2048),   blk, 0, stream>>>(S, PXv);
  k_pv     <<<dim3(32,1,8), dim3(512), 0, stream>>>(PXv, vT, out);
}